// Round 13
// baseline (181.635 us; speedup 1.0000x reference)
//
#include <hip/hip_runtime.h>
#include <hip/hip_bf16.h>
#include <float.h>
#include <math.h>

#define BB 64
#define NNtok 197
#define DD 768
#define HH 12
#define PP 12
#define CC 200
#define NPATCH 196

typedef short bf16x8 __attribute__((ext_vector_type(8)));
typedef float f32x4 __attribute__((ext_vector_type(4)));

__device__ __forceinline__ unsigned short bf16_bits(float x) {
  __hip_bfloat16 h = __float2bfloat16(x);
  return *reinterpret_cast<unsigned short*>(&h);
}
__device__ __forceinline__ float bfu(unsigned short us) {
  union { unsigned int u; float f; } cv; cv.u = ((unsigned int)us) << 16; return cv.f;
}
__device__ __forceinline__ bf16x8 cvt8(float4 a, float4 b) {
  union { unsigned short u[8]; bf16x8 v; } r;
  r.u[0] = bf16_bits(a.x); r.u[1] = bf16_bits(a.y);
  r.u[2] = bf16_bits(a.z); r.u[3] = bf16_bits(a.w);
  r.u[4] = bf16_bits(b.x); r.u[5] = bf16_bits(b.y);
  r.u[6] = bf16_bits(b.z); r.u[7] = bf16_bits(b.w);
  return r.v;
}

// LDS offsets (bytes) for kA
#define OS_PARTS 0      // ushort[2][12][776] = 37248  (dead after G1)
#define OS_O3 0         // ushort[2][16][192] = 12288  (aliases parts)
#define OS_SCORES 12288 // float[432] = 1728           (aliases parts)
#define OS_SC 14016     // float[256] = 1024           (select only, pre-parts)
#define OS_QKV 37248    // ushort[2][3][16][192] = 36864
#define OS_SEL 74112    // int[2][12] = 96
#define SMB_A 74208

// ====== kA: per (b-pair, hg): select+LN1 + qkv GEMM + attn + partial wout ===
__global__ __launch_bounds__(256, 1) void kA_mid(
    const float* __restrict__ hidden, const float* __restrict__ attns,
    const float* __restrict__ ln1_g, const float* __restrict__ ln1_b,
    const float* __restrict__ w_in, const float* __restrict__ b_in,
    const float* __restrict__ w_out, float* __restrict__ part_ws) {
  __shared__ __align__(16) char sm[SMB_A];
  int t = threadIdx.x, blk = blockIdx.x;
  int wv = t >> 6, ln = t & 63;
  int hg = blk & 3, bp = blk >> 2;
  int b0 = bp * 2;
  unsigned short* partsL = (unsigned short*)(sm + OS_PARTS);
  unsigned short* qkvp = (unsigned short*)(sm + OS_QKV);
  unsigned short* o3p = (unsigned short*)(sm + OS_O3);
  float* scores = (float*)(sm + OS_SCORES);
  float* sc = (float*)(sm + OS_SC);
  int* sel_s = (int*)(sm + OS_SEL);

  // ---- Phase S: select + top-12 for both batches (redundant per hg) -------
#pragma unroll
  for (int bq = 0; bq < 2; bq++) {
    int b = b0 + bq;
    float acc = -FLT_MAX;
    if (t < NPATCH) {
      acc = 0.f;
#pragma unroll
      for (int l = 0; l < 4; l++) {
        float part = 0.f;
#pragma unroll
        for (int h = 0; h < HH; h++) {
          size_t base = (size_t)((l * BB + b) * HH + h) * ((size_t)NNtok * NNtok);
          part += attns[base + 1 + t];
        }
        acc += part * (1.f / 12.f);
      }
      acc *= 0.25f;
    }
    sc[t] = acc;
    __syncthreads();
    if (t < 64) {
      float v[4]; int idx[4];
#pragma unroll
      for (int j = 0; j < 4; j++) { idx[j] = t + j * 64; v[j] = sc[idx[j]]; }
      for (int it = 0; it < PP; ++it) {
        float bv = v[0]; int bidx = idx[0];
#pragma unroll
        for (int j = 1; j < 4; j++)
          if (v[j] > bv || (v[j] == bv && idx[j] < bidx)) { bv = v[j]; bidx = idx[j]; }
        float cv = bv; int ci = bidx;
#pragma unroll
        for (int off = 32; off > 0; off >>= 1) {
          float ov = __shfl_xor(cv, off); int oi = __shfl_xor(ci, off);
          if (ov > cv || (ov == cv && oi < ci)) { cv = ov; ci = oi; }
        }
        if (t == 0) sel_s[bq * 12 + it] = ci;
#pragma unroll
        for (int j = 0; j < 4; j++)
          if (idx[j] == ci) v[j] = -FLT_MAX;
      }
    }
    __syncthreads();
  }

  // ---- gather + LN1 -> partsL (wave wv: rows wv*3..wv*3+2, both batches) --
#pragma unroll
  for (int q = 0; q < 3; q++) {
    int i = wv * 3 + q;
#pragma unroll
    for (int bq = 0; bq < 2; bq++) {
      const float* row =
          hidden + ((size_t)(b0 + bq) * NNtok + 1 + sel_s[bq * 12 + i]) * DD;
      float x[12], s1 = 0.f, s2 = 0.f;
#pragma unroll
      for (int k = 0; k < 12; k++) {
        x[k] = row[ln + 64 * k];
        s1 += x[k]; s2 += x[k] * x[k];
      }
#pragma unroll
      for (int off = 32; off > 0; off >>= 1) {
        s1 += __shfl_xor(s1, off); s2 += __shfl_xor(s2, off);
      }
      float m = s1 * (1.f / DD);
      float rstd = rsqrtf(s2 * (1.f / DD) - m * m + 1e-5f);
#pragma unroll
      for (int k = 0; k < 12; k++) {
        int d = ln + 64 * k;
        partsL[(bq * 12 + i) * 776 + d] =
            bf16_bits((x[k] - m) * rstd * ln1_g[d] + ln1_b[d]);
      }
    }
  }
  __syncthreads();

  // ---- Phase G1: qkv slice = parts @ W_in[hg]^T (f32 weights, inline cvt) -
  {
    int lr = ln & 15, kg = ln >> 4;
    int pr = lr < 12 ? lr : 11;
    int wrow[9];
#pragma unroll
    for (int nf = 0; nf < 9; nf++) {
      int lc = wv * 144 + nf * 16 + lr;
      int s = lc / 192, d2 = lc - s * 192;
      wrow[nf] = s * 768 + hg * 192 + d2;
    }
    f32x4 acc[2][9];
#pragma unroll
    for (int bq = 0; bq < 2; bq++)
#pragma unroll
      for (int nf = 0; nf < 9; nf++) {
        acc[bq][nf][0] = 0.f; acc[bq][nf][1] = 0.f;
        acc[bq][nf][2] = 0.f; acc[bq][nf][3] = 0.f;
      }
    for (int k0 = 0; k0 < 768; k0 += 32) {
      bf16x8 af0 = *(const bf16x8*)(partsL + (0 * 12 + pr) * 776 + kg * 8 + k0);
      bf16x8 af1 = *(const bf16x8*)(partsL + (1 * 12 + pr) * 776 + kg * 8 + k0);
#pragma unroll
      for (int nf = 0; nf < 9; nf++) {
        const float* wp = w_in + (size_t)wrow[nf] * DD + kg * 8 + k0;
        bf16x8 wf = cvt8(*(const float4*)wp, *(const float4*)(wp + 4));
        acc[0][nf] = __builtin_amdgcn_mfma_f32_16x16x32_bf16(af0, wf, acc[0][nf], 0, 0, 0);
        acc[1][nf] = __builtin_amdgcn_mfma_f32_16x16x32_bf16(af1, wf, acc[1][nf], 0, 0, 0);
      }
    }
    __syncthreads();  // partsL dead; o3/scores region reuse comes later
#pragma unroll
    for (int nf = 0; nf < 9; nf++) {
      int lc = wv * 144 + nf * 16 + lr;
      int s = lc / 192, d2 = lc - s * 192;
      float bv = b_in[s * 768 + hg * 192 + d2];
#pragma unroll
      for (int r = 0; r < 4; r++) {
        int p = kg * 4 + r;
        if (p < 12) {
          qkvp[(0 * 48 + s * 16 + p) * 192 + d2] = bf16_bits(acc[0][nf][r] + bv);
          qkvp[(1 * 48 + s * 16 + p) * 192 + d2] = bf16_bits(acc[1][nf][r] + bv);
        }
      }
    }
  }
  __syncthreads();

  // ---- Phase At: 3-head attention per batch -------------------------------
#pragma unroll
  for (int bq = 0; bq < 2; bq++) {
    const unsigned short* qk = qkvp + bq * 9216;
    unsigned short* o3 = o3p + bq * 3072;
    for (int e = t; e < 432; e += 256) {
      int h = e / 144, rem = e - h * 144;
      int i = rem / 12, j = rem - i * 12;
      float s = 0.f;
#pragma unroll
      for (int d = 0; d < 64; d++)
        s += bfu(qk[(0 * 16 + i) * 192 + h * 64 + d]) *
             bfu(qk[(1 * 16 + j) * 192 + h * 64 + d]);
      scores[e] = s * 0.125f;
    }
    __syncthreads();
    if (t < 36) {
      int h = t / 12, i = t - h * 12;
      float* row = scores + h * 144 + i * 12;
      float m = -FLT_MAX;
#pragma unroll
      for (int j = 0; j < 12; j++) m = fmaxf(m, row[j]);
      float e2[12], sum = 0.f;
#pragma unroll
      for (int j = 0; j < 12; j++) { e2[j] = expf(row[j] - m); sum += e2[j]; }
      float inv = 1.f / sum;
#pragma unroll
      for (int j = 0; j < 12; j++) row[j] = e2[j] * inv;
    }
    __syncthreads();
    for (int o = t; o < 2304; o += 256) {
      int i = o / 192, d2 = o - i * 192;
      int h = d2 >> 6;
      float s = 0.f;
#pragma unroll
      for (int j = 0; j < 12; j++)
        s += scores[h * 144 + i * 12 + j] * bfu(qk[(2 * 16 + j) * 192 + d2]);
      o3[i * 192 + d2] = bf16_bits(s);
    }
    __syncthreads();
  }

  // ---- Phase G2: partial wout (f32 weights, inline cvt) -> part_ws --------
  {
    int lr = ln & 15, kg = ln >> 4;
    f32x4 acc2[2][12];
#pragma unroll
    for (int bq = 0; bq < 2; bq++)
#pragma unroll
      for (int jf = 0; jf < 12; jf++) {
        acc2[bq][jf][0] = 0.f; acc2[bq][jf][1] = 0.f;
        acc2[bq][jf][2] = 0.f; acc2[bq][jf][3] = 0.f;
      }
    for (int k0 = 0; k0 < 192; k0 += 32) {
      bf16x8 af0 = *(const bf16x8*)(o3p + 0 * 3072 + lr * 192 + kg * 8 + k0);
      bf16x8 af1 = *(const bf16x8*)(o3p + 1 * 3072 + lr * 192 + kg * 8 + k0);
#pragma unroll
      for (int jf = 0; jf < 12; jf++) {
        int j = wv * 192 + jf * 16 + lr;
        const float* wp = w_out + (size_t)j * DD + hg * 192 + kg * 8 + k0;
        bf16x8 wf = cvt8(*(const float4*)wp, *(const float4*)(wp + 4));
        acc2[0][jf] = __builtin_amdgcn_mfma_f32_16x16x32_bf16(af0, wf, acc2[0][jf], 0, 0, 0);
        acc2[1][jf] = __builtin_amdgcn_mfma_f32_16x16x32_bf16(af1, wf, acc2[1][jf], 0, 0, 0);
      }
    }
#pragma unroll
    for (int jf = 0; jf < 12; jf++) {
      int j = wv * 192 + jf * 16 + lr;
#pragma unroll
      for (int r = 0; r < 4; r++) {
        int p = kg * 4 + r;
        if (p < 12) {
          part_ws[(((size_t)b0 * 4 + hg) * 12 + p) * DD + j] = acc2[0][jf][r];
          part_ws[(((size_t)(b0 + 1) * 4 + hg) * 12 + p) * DD + j] = acc2[1][jf][r];
        }
      }
    }
  }
}

// ====== kB: per (b,q4): reduce partials + LN2 + pool + MLP slice (f32) ======
__global__ __launch_bounds__(256) void kB_back(
    const float* __restrict__ part_ws, const float* __restrict__ b_out,
    const float* __restrict__ g, const float* __restrict__ be,
    const float* __restrict__ wp, const float* __restrict__ bp,
    const float* __restrict__ ptemp, const float* __restrict__ w_mlp,
    const float* __restrict__ bmlp, float* __restrict__ pmlp) {
  int bi = blockIdx.x;
  int b = bi >> 2, q4 = bi & 3;
  int t = threadIdx.x, wv = t >> 6, ln = t & 63;
  __shared__ float a12[12 * 768];
  __shared__ float raww_s[12];
  __shared__ float pfeat[768];
  for (int u = t; u < 9216; u += 256) {
    int j = u % 768;
    float s = b_out[j];
#pragma unroll
    for (int hg = 0; hg < 4; hg++)
      s += part_ws[(((size_t)b * 4 + hg) * 12) * DD + u];
    a12[u] = s;
  }
  __syncthreads();
#pragma unroll
  for (int q = 0; q < 3; q++) {
    int r = wv * 3 + q;
    float x[12], s1 = 0.f, s2 = 0.f;
#pragma unroll
    for (int k = 0; k < 12; k++) {
      x[k] = a12[r * 768 + ln + 64 * k];
      s1 += x[k]; s2 += x[k] * x[k];
    }
#pragma unroll
    for (int off = 32; off > 0; off >>= 1) {
      s1 += __shfl_xor(s1, off); s2 += __shfl_xor(s2, off);
    }
    float m = s1 * (1.f / DD);
    float rstd = rsqrtf(s2 * (1.f / DD) - m * m + 1e-5f);
    float pl = 0.f;
#pragma unroll
    for (int k = 0; k < 12; k++) {
      int d = ln + 64 * k;
      float y = (x[k] - m) * rstd * g[d] + be[d];
      a12[r * 768 + d] = y;
      pl += y * wp[d];
    }
#pragma unroll
    for (int off = 32; off > 0; off >>= 1) pl += __shfl_xor(pl, off);
    if (ln == 0) raww_s[r] = pl + bp[0];
  }
  __syncthreads();
  float wts[12];
  {
    float inv = 1.f / fmaxf(ptemp[0], 0.3f);
    float z[12], mx = -FLT_MAX;
#pragma unroll
    for (int p = 0; p < 12; p++) { z[p] = raww_s[p] * inv; mx = fmaxf(mx, z[p]); }
    float s = 0.f;
#pragma unroll
    for (int p = 0; p < 12; p++) { z[p] = expf(z[p] - mx); s += z[p]; }
    float is = 1.f / s;
#pragma unroll
    for (int p = 0; p < 12; p++) wts[p] = z[p] * is;
  }
  for (int d = t; d < 768; d += 256) {
    float s = 0.f;
#pragma unroll
    for (int p = 0; p < 12; p++) s += a12[p * 768 + d] * wts[p];
    pfeat[d] = s;
  }
  __syncthreads();
  if (t < 192) {
    int j = q4 * 192 + t;
    const float4* wr = (const float4*)(w_mlp + (size_t)j * DD);
    float acc2 = bmlp[j];
    for (int k = 0; k < 192; k++) {
      float4 w4 = wr[k];
      const float* pf = &pfeat[k * 4];
      acc2 += pf[0] * w4.x + pf[1] * w4.y + pf[2] * w4.z + pf[3] * w4.w;
    }
    pmlp[(size_t)b * DD + j] = fmaxf(acc2, 0.f);
  }
}

// ====== kC: fusion norm + arc_w norms + ArcFace, 16 classes/block ===========
__global__ __launch_bounds__(256) void kC_arc(
    const float* __restrict__ hidden, const float* __restrict__ pmlp,
    const float* __restrict__ aw, const int* __restrict__ labels,
    float* __restrict__ out) {
  int cb = blockIdx.x, b = blockIdx.y, t = threadIdx.x;
  int wv = t >> 6, ln = t & 63;
  __shared__ float4 fs4[384];
  __shared__ float a4[4];
  const float4* cls4 = (const float4*)(hidden + (size_t)b * NNtok * DD);
  const float4* pm4 = (const float4*)(pmlp + (size_t)b * DD);
  for (int u = t; u < 384; u += 256) fs4[u] = (u < 192) ? cls4[u] : pm4[u - 192];
  __syncthreads();
  float s = 0.f;
  for (int u = t; u < 384; u += 256) {
    float4 v = fs4[u];
    s += v.x * v.x + v.y * v.y + v.z * v.z + v.w * v.w;
  }
#pragma unroll
  for (int off = 32; off > 0; off >>= 1) s += __shfl_xor(s, off);
  if (ln == 0) a4[wv] = s;
  __syncthreads();
  float rnf = rsqrtf(a4[0] + a4[1] + a4[2] + a4[3]);
  int lab = labels[b];
  const float cos_m = 0.8775825618903728f, sin_m = 0.479425538604203f;
  const float th = -0.8775825618903728f, mm = 0.2397127693021015f;
#pragma unroll
  for (int ci = 0; ci < 4; ci++) {
    int c = cb * 16 + ci * 4 + wv;
    if (c < CC) {
      const float4* wr = (const float4*)(aw + (size_t)c * 1536);
      float acc = 0.f, nw = 0.f;
#pragma unroll
      for (int k = 0; k < 6; k++) {
        float4 a = fs4[ln + 64 * k];
        float4 w = wr[ln + 64 * k];
        acc += a.x * w.x + a.y * w.y + a.z * w.z + a.w * w.w;
        nw += w.x * w.x + w.y * w.y + w.z * w.z + w.w * w.w;
      }
#pragma unroll
      for (int off = 32; off > 0; off >>= 1) {
        acc += __shfl_xor(acc, off); nw += __shfl_xor(nw, off);
      }
      if (ln == 0) {
        float cosv = acc * rsqrtf(nw) * rnf;
        float s2 = 1.f - cosv * cosv;
        s2 = fminf(fmaxf(s2, 0.f), 1.f);
        float sinv = sqrtf(s2);
        float phi = cosv * cos_m - sinv * sin_m;
        phi = (cosv > th) ? phi : (cosv - mm);
        out[(size_t)b * CC + c] = ((c == lab) ? phi : cosv) * 30.f;
      }
    }
  }
}

extern "C" void kernel_launch(void* const* d_in, const int* in_sizes, int n_in,
                              void* d_out, int out_size, void* d_ws, size_t ws_size,
                              hipStream_t stream) {
  const float* hidden = (const float*)d_in[0];
  const float* attns  = (const float*)d_in[1];
  const int*   labels = (const int*)d_in[2];
  const float* ln1_g  = (const float*)d_in[3];
  const float* ln1_b  = (const float*)d_in[4];
  const float* w_in   = (const float*)d_in[5];
  const float* b_in   = (const float*)d_in[6];
  const float* w_out  = (const float*)d_in[7];
  const float* b_out  = (const float*)d_in[8];
  const float* ln2_g  = (const float*)d_in[9];
  const float* ln2_b  = (const float*)d_in[10];
  const float* w_pool = (const float*)d_in[11];
  const float* b_pool = (const float*)d_in[12];
  const float* ptemp  = (const float*)d_in[13];
  const float* w_mlp  = (const float*)d_in[14];
  const float* b_mlp  = (const float*)d_in[15];
  const float* arc_w  = (const float*)d_in[16];
  float* outp = (float*)d_out;

  float* F = (float*)d_ws;
  float* part_ws = F;            // 2359296 f32
  float* pmlp = F + 2359296;     // 49152 f32

  kA_mid<<<128, 256, 0, stream>>>(hidden, attns, ln1_g, ln1_b, w_in, b_in,
                                  w_out, part_ws);
  kB_back<<<256, 256, 0, stream>>>(part_ws, b_out, ln2_g, ln2_b, w_pool, b_pool,
                                   ptemp, w_mlp, b_mlp, pmlp);
  kC_arc<<<dim3(13, BB), 256, 0, stream>>>(hidden, pmlp, arc_w, labels, outp);
}

// Round 14
// 89.626 us; speedup vs baseline: 2.0266x; 2.0266x over previous
//
#include <hip/hip_runtime.h>
#include <hip/hip_bf16.h>
#include <float.h>
#include <math.h>

#define BB 64
#define NNtok 197
#define DD 768
#define HH 12
#define PP 12
#define CC 200
#define NPATCH 196

typedef short bf16x8 __attribute__((ext_vector_type(8)));
typedef float f32x4 __attribute__((ext_vector_type(4)));

__device__ __forceinline__ unsigned short bf16_bits(float x) {
  __hip_bfloat16 h = __float2bfloat16(x);
  return *reinterpret_cast<unsigned short*>(&h);
}
__device__ __forceinline__ float u2f(unsigned int u) {
  union { unsigned int u; float f; } cv; cv.u = u; return cv.f;
}
__device__ __forceinline__ float bfu(unsigned short us) {
  union { unsigned int u; float f; } cv; cv.u = ((unsigned int)us) << 16; return cv.f;
}

// ================= K1: select+top12+LN1 (blk<64) | weight casts =============
__global__ __launch_bounds__(256) void k1_front(
    const float* __restrict__ hidden, const float* __restrict__ attns,
    const float* __restrict__ g, const float* __restrict__ be,
    const float* __restrict__ w1, const float* __restrict__ w2,
    const float* __restrict__ w3, __hip_bfloat16* __restrict__ o1,
    __hip_bfloat16* __restrict__ o2, __hip_bfloat16* __restrict__ o3,
    __hip_bfloat16* __restrict__ parts) {
  int t = threadIdx.x, bi = blockIdx.x;
  if (bi >= 64) {
    for (int i = (bi - 64) * 256 + t; i < 737280; i += 256 * 256) {
      const float* src; __hip_bfloat16* dst; int off;
      if (i < 442368) { src = w1; dst = o1; off = i; }
      else if (i < 589824) { src = w2; dst = o2; off = i - 442368; }
      else { src = w3; dst = o3; off = i - 589824; }
      float4 v = ((const float4*)src)[off];
      union { unsigned short u[4]; ushort4 v4; } p;
      p.u[0] = bf16_bits(v.x); p.u[1] = bf16_bits(v.y);
      p.u[2] = bf16_bits(v.z); p.u[3] = bf16_bits(v.w);
      ((ushort4*)dst)[off] = p.v4;
    }
    return;
  }
  int b = bi;
  __shared__ float sc[256];
  __shared__ int sel_s[PP];
  int wv = t >> 6, ln = t & 63;
  float acc = -FLT_MAX;
  if (t < NPATCH) {
    acc = 0.f;
#pragma unroll
    for (int l = 0; l < 4; l++) {
      float part = 0.f;
#pragma unroll
      for (int h = 0; h < HH; h++) {
        size_t base = (size_t)((l * BB + b) * HH + h) * ((size_t)NNtok * NNtok);
        part += attns[base + 1 + t];
      }
      acc += part * (1.f / 12.f);
    }
    acc *= 0.25f;
  }
  sc[t] = acc;
  __syncthreads();
  if (t < 64) {
    float v[4]; int idx[4];
#pragma unroll
    for (int j = 0; j < 4; j++) { idx[j] = t + j * 64; v[j] = sc[idx[j]]; }
    for (int it = 0; it < PP; ++it) {
      float bv = v[0]; int bidx = idx[0];
#pragma unroll
      for (int j = 1; j < 4; j++)
        if (v[j] > bv || (v[j] == bv && idx[j] < bidx)) { bv = v[j]; bidx = idx[j]; }
      float cv = bv; int ci = bidx;
#pragma unroll
      for (int off = 32; off > 0; off >>= 1) {
        float ov = __shfl_xor(cv, off); int oi = __shfl_xor(ci, off);
        if (ov > cv || (ov == cv && oi < ci)) { cv = ov; ci = oi; }
      }
      if (t == 0) sel_s[it] = ci;
#pragma unroll
      for (int j = 0; j < 4; j++)
        if (idx[j] == ci) v[j] = -FLT_MAX;
    }
  }
  __syncthreads();
#pragma unroll
  for (int q = 0; q < 3; q++) {
    int i = wv * 3 + q;
    const float* row = hidden + ((size_t)b * NNtok + 1 + sel_s[i]) * DD;
    float x[12], s1 = 0.f, s2 = 0.f;
#pragma unroll
    for (int k = 0; k < 12; k++) {
      x[k] = row[ln + 64 * k];
      s1 += x[k]; s2 += x[k] * x[k];
    }
#pragma unroll
    for (int off = 32; off > 0; off >>= 1) {
      s1 += __shfl_xor(s1, off); s2 += __shfl_xor(s2, off);
    }
    float m = s1 * (1.f / DD);
    float rstd = rsqrtf(s2 * (1.f / DD) - m * m + 1e-5f);
    __hip_bfloat16* outp_ = parts + ((size_t)b * PP + i) * DD;
#pragma unroll
    for (int k = 0; k < 12; k++) {
      int d = ln + 64 * k;
      outp_[d] = __float2bfloat16((x[k] - m) * rstd * g[d] + be[d]);
    }
  }
}

// ====== K2: per (b,hg): qkv-slice GEMM + 3-head attention + partial wout ====
__global__ __launch_bounds__(256) void k2_mid(
    const __hip_bfloat16* __restrict__ parts, const __hip_bfloat16* __restrict__ w_in_bf,
    const float* __restrict__ b_in, const __hip_bfloat16* __restrict__ w_out_bf,
    __hip_bfloat16* __restrict__ part_ws) {
  int bi = blockIdx.x;
  int b = bi >> 2, hg = bi & 3;  // hg = XCD&3 under round-robin: slice L2-pinned
  int t = threadIdx.x;
  int wave = t >> 6, lane = t & 63, lr = lane & 15, kg = lane >> 4;
  __shared__ __align__(16) unsigned short qkv3[3][16][192];
  __shared__ __align__(16) unsigned short o3[16][192];
  __shared__ float scores[432];

  int pr = lr < 12 ? lr : 11;
  const __hip_bfloat16* Ab = parts + ((size_t)b * 12 + pr) * DD + kg * 8;
  int wrow[9];
#pragma unroll
  for (int nf = 0; nf < 9; nf++) {
    int lc = wave * 144 + nf * 16 + lr;
    int s = lc / 192, d2 = lc - s * 192;
    wrow[nf] = s * 768 + hg * 192 + d2;
  }
  f32x4 acc[9];
#pragma unroll
  for (int nf = 0; nf < 9; nf++) { acc[nf][0]=0.f; acc[nf][1]=0.f; acc[nf][2]=0.f; acc[nf][3]=0.f; }
  for (int k0 = 0; k0 < 768; k0 += 32) {
    bf16x8 af = *(const bf16x8*)(Ab + k0);
    bf16x8 wf[9];
#pragma unroll
    for (int nf = 0; nf < 9; nf++)
      wf[nf] = *(const bf16x8*)(w_in_bf + (size_t)wrow[nf] * DD + kg * 8 + k0);
#pragma unroll
    for (int nf = 0; nf < 9; nf++)
      acc[nf] = __builtin_amdgcn_mfma_f32_16x16x32_bf16(af, wf[nf], acc[nf], 0, 0, 0);
  }
#pragma unroll
  for (int nf = 0; nf < 9; nf++) {
    int lc = wave * 144 + nf * 16 + lr;
    int s = lc / 192, d2 = lc - s * 192;
    float bv = b_in[s * 768 + hg * 192 + d2];
#pragma unroll
    for (int r = 0; r < 4; r++) {
      int p = kg * 4 + r;
      qkv3[s][p][d2] = bf16_bits(acc[nf][r] + bv);
    }
  }
  __syncthreads();

  for (int e = t; e < 432; e += 256) {
    int h = e / 144, rem = e - h * 144;
    int i = rem / 12, j = rem - i * 12;
    float s = 0.f;
#pragma unroll
    for (int d = 0; d < 64; d++)
      s += bfu(qkv3[0][i][h * 64 + d]) * bfu(qkv3[1][j][h * 64 + d]);
    scores[e] = s * 0.125f;
  }
  __syncthreads();
  if (t < 36) {
    int h = t / 12, i = t - h * 12;
    float* row = scores + h * 144 + i * 12;
    float m = -FLT_MAX;
#pragma unroll
    for (int j = 0; j < 12; j++) m = fmaxf(m, row[j]);
    float e2[12], sum = 0.f;
#pragma unroll
    for (int j = 0; j < 12; j++) { e2[j] = expf(row[j] - m); sum += e2[j]; }
    float inv = 1.f / sum;
#pragma unroll
    for (int j = 0; j < 12; j++) row[j] = e2[j] * inv;
  }
  __syncthreads();
  for (int o = t; o < 2304; o += 256) {
    int i = o / 192, d2 = o - i * 192;
    int h = d2 >> 6;
    float s = 0.f;
#pragma unroll
    for (int j = 0; j < 12; j++)
      s += scores[h * 144 + i * 12 + j] * bfu(qkv3[2][j][d2]);
    o3[i][d2] = bf16_bits(s);
  }
  __syncthreads();

  f32x4 acc2[12];
#pragma unroll
  for (int jf = 0; jf < 12; jf++) { acc2[jf][0]=0.f; acc2[jf][1]=0.f; acc2[jf][2]=0.f; acc2[jf][3]=0.f; }
  const unsigned short* Ob = &o3[0][0] + lr * 192 + kg * 8;
  for (int k0 = 0; k0 < 192; k0 += 32) {
    bf16x8 af = *(const bf16x8*)(Ob + k0);
    bf16x8 wf[12];
#pragma unroll
    for (int jf = 0; jf < 12; jf++) {
      int j = wave * 192 + jf * 16 + lr;
      wf[jf] = *(const bf16x8*)(w_out_bf + (size_t)j * DD + hg * 192 + kg * 8 + k0);
    }
#pragma unroll
    for (int jf = 0; jf < 12; jf++)
      acc2[jf] = __builtin_amdgcn_mfma_f32_16x16x32_bf16(af, wf[jf], acc2[jf], 0, 0, 0);
  }
#pragma unroll
  for (int jf = 0; jf < 12; jf++) {
    int j = wave * 192 + jf * 16 + lr;
#pragma unroll
    for (int r = 0; r < 4; r++) {
      int p = kg * 4 + r;
      if (p < 12)
        part_ws[(((size_t)b * 4 + hg) * 12 + p) * DD + j] =
            __float2bfloat16(acc2[jf][r]);
    }
  }
}

// ====== K3: per (b,q4): reduce partials + LN2 + pool + MLP slice ============
__global__ __launch_bounds__(256) void k3_back(
    const __hip_bfloat16* __restrict__ part_ws, const float* __restrict__ b_out,
    const float* __restrict__ g, const float* __restrict__ be,
    const float* __restrict__ wp, const float* __restrict__ bp,
    const float* __restrict__ ptemp, const __hip_bfloat16* __restrict__ wmlp,
    const float* __restrict__ bmlp, float* __restrict__ pmlp) {
  int bi = blockIdx.x;
  int b = bi >> 2, q4 = bi & 3;
  int t = threadIdx.x, wv = t >> 6, ln = t & 63;
  __shared__ float a12[12 * 768];
  __shared__ float raww_s[12];
  __shared__ float pfeat[768];
  for (int u = t; u < 9216; u += 256) {
    int j = u % 768;
    float s = b_out[j];
#pragma unroll
    for (int hg = 0; hg < 4; hg++)
      s += __bfloat162float(part_ws[(((size_t)b * 4 + hg) * 12) * DD + u]);
    a12[u] = s;
  }
  __syncthreads();
#pragma unroll
  for (int q = 0; q < 3; q++) {
    int r = wv * 3 + q;
    float x[12], s1 = 0.f, s2 = 0.f;
#pragma unroll
    for (int k = 0; k < 12; k++) {
      x[k] = a12[r * 768 + ln + 64 * k];
      s1 += x[k]; s2 += x[k] * x[k];
    }
#pragma unroll
    for (int off = 32; off > 0; off >>= 1) {
      s1 += __shfl_xor(s1, off); s2 += __shfl_xor(s2, off);
    }
    float m = s1 * (1.f / DD);
    float rstd = rsqrtf(s2 * (1.f / DD) - m * m + 1e-5f);
    float pl = 0.f;
#pragma unroll
    for (int k = 0; k < 12; k++) {
      int d = ln + 64 * k;
      float y = (x[k] - m) * rstd * g[d] + be[d];
      a12[r * 768 + d] = y;
      pl += y * wp[d];
    }
#pragma unroll
    for (int off = 32; off > 0; off >>= 1) pl += __shfl_xor(pl, off);
    if (ln == 0) raww_s[r] = pl + bp[0];
  }
  __syncthreads();
  float wts[12];
  {
    float inv = 1.f / fmaxf(ptemp[0], 0.3f);
    float z[12], mx = -FLT_MAX;
#pragma unroll
    for (int p = 0; p < 12; p++) { z[p] = raww_s[p] * inv; mx = fmaxf(mx, z[p]); }
    float s = 0.f;
#pragma unroll
    for (int p = 0; p < 12; p++) { z[p] = expf(z[p] - mx); s += z[p]; }
    float is = 1.f / s;
#pragma unroll
    for (int p = 0; p < 12; p++) wts[p] = z[p] * is;
  }
  for (int d = t; d < 768; d += 256) {
    float s = 0.f;
#pragma unroll
    for (int p = 0; p < 12; p++) s += a12[p * 768 + d] * wts[p];
    pfeat[d] = s;
  }
  __syncthreads();
  if (t < 192) {
    int j = q4 * 192 + t;
    const uint4* wr = (const uint4*)(wmlp + (size_t)j * DD);
    float acc2 = bmlp[j];
    for (int k = 0; k < 96; k++) {
      uint4 w4 = wr[k];
      const float* pf = &pfeat[k * 8];
      acc2 += pf[0] * u2f(w4.x << 16) + pf[1] * u2f(w4.x & 0xFFFF0000u)
            + pf[2] * u2f(w4.y << 16) + pf[3] * u2f(w4.y & 0xFFFF0000u)
            + pf[4] * u2f(w4.z << 16) + pf[5] * u2f(w4.z & 0xFFFF0000u)
            + pf[6] * u2f(w4.w << 16) + pf[7] * u2f(w4.w & 0xFFFF0000u);
    }
    pmlp[(size_t)b * DD + j] = fmaxf(acc2, 0.f);
  }
}

// ====== K4: fusion norm + arc_w norms + ArcFace, 16 classes/block ===========
__global__ __launch_bounds__(256) void k4_arc(
    const float* __restrict__ hidden, const float* __restrict__ pmlp,
    const float* __restrict__ aw, const int* __restrict__ labels,
    float* __restrict__ out) {
  int cb = blockIdx.x, b = blockIdx.y, t = threadIdx.x;
  int wv = t >> 6, ln = t & 63;
  __shared__ float4 fs4[384];
  __shared__ float a4[4];
  const float4* cls4 = (const float4*)(hidden + (size_t)b * NNtok * DD);
  const float4* pm4 = (const float4*)(pmlp + (size_t)b * DD);
  for (int u = t; u < 384; u += 256) fs4[u] = (u < 192) ? cls4[u] : pm4[u - 192];
  __syncthreads();
  float s = 0.f;
  for (int u = t; u < 384; u += 256) {
    float4 v = fs4[u];
    s += v.x * v.x + v.y * v.y + v.z * v.z + v.w * v.w;
  }
#pragma unroll
  for (int off = 32; off > 0; off >>= 1) s += __shfl_xor(s, off);
  if (ln == 0) a4[wv] = s;
  __syncthreads();
  float rnf = rsqrtf(a4[0] + a4[1] + a4[2] + a4[3]);
  int lab = labels[b];
  const float cos_m = 0.8775825618903728f, sin_m = 0.479425538604203f;
  const float th = -0.8775825618903728f, mm = 0.2397127693021015f;
#pragma unroll
  for (int ci = 0; ci < 4; ci++) {
    int c = cb * 16 + ci * 4 + wv;
    if (c < CC) {
      const float4* wr = (const float4*)(aw + (size_t)c * 1536);
      float acc = 0.f, nw = 0.f;
#pragma unroll
      for (int k = 0; k < 6; k++) {
        float4 a = fs4[ln + 64 * k];
        float4 w = wr[ln + 64 * k];
        acc += a.x * w.x + a.y * w.y + a.z * w.z + a.w * w.w;
        nw += w.x * w.x + w.y * w.y + w.z * w.z + w.w * w.w;
      }
#pragma unroll
      for (int off = 32; off > 0; off >>= 1) {
        acc += __shfl_xor(acc, off); nw += __shfl_xor(nw, off);
      }
      if (ln == 0) {
        float cosv = acc * rsqrtf(nw) * rnf;
        float s2 = 1.f - cosv * cosv;
        s2 = fminf(fmaxf(s2, 0.f), 1.f);
        float sinv = sqrtf(s2);
        float phi = cosv * cos_m - sinv * sin_m;
        phi = (cosv > th) ? phi : (cosv - mm);
        out[(size_t)b * CC + c] = ((c == lab) ? phi : cosv) * 30.f;
      }
    }
  }
}

extern "C" void kernel_launch(void* const* d_in, const int* in_sizes, int n_in,
                              void* d_out, int out_size, void* d_ws, size_t ws_size,
                              hipStream_t stream) {
  const float* hidden = (const float*)d_in[0];
  const float* attns  = (const float*)d_in[1];
  const int*   labels = (const int*)d_in[2];
  const float* ln1_g  = (const float*)d_in[3];
  const float* ln1_b  = (const float*)d_in[4];
  const float* w_in   = (const float*)d_in[5];
  const float* b_in   = (const float*)d_in[6];
  const float* w_out  = (const float*)d_in[7];
  const float* b_out  = (const float*)d_in[8];
  const float* ln2_g  = (const float*)d_in[9];
  const float* ln2_b  = (const float*)d_in[10];
  const float* w_pool = (const float*)d_in[11];
  const float* b_pool = (const float*)d_in[12];
  const float* ptemp  = (const float*)d_in[13];
  const float* w_mlp  = (const float*)d_in[14];
  const float* b_mlp  = (const float*)d_in[15];
  const float* arc_w  = (const float*)d_in[16];
  float* outp = (float*)d_out;

  float* F = (float*)d_ws;
  __hip_bfloat16* part_ws = (__hip_bfloat16*)F;                // 2359296 bf16 (1179648 f)
  float* pmlp = F + 1179648;                                   // 49152 f32
  __hip_bfloat16* parts_bf = (__hip_bfloat16*)(F + 1228800);   // 589824 bf16
  __hip_bfloat16* w_in_bf  = (__hip_bfloat16*)(F + 1523712);   // 1769472 bf16
  __hip_bfloat16* w_out_bf = (__hip_bfloat16*)(F + 2408448);   // 589824 bf16
  __hip_bfloat16* w_mlp_bf = (__hip_bfloat16*)(F + 2703360);   // 589824 bf16

  k1_front<<<320, 256, 0, stream>>>(hidden, attns, ln1_g, ln1_b, w_in, w_out,
                                    w_mlp, w_in_bf, w_out_bf, w_mlp_bf, parts_bf);
  k2_mid<<<256, 256, 0, stream>>>(parts_bf, w_in_bf, b_in, w_out_bf, part_ws);
  k3_back<<<256, 256, 0, stream>>>(part_ws, b_out, ln2_g, ln2_b, w_pool, b_pool,
                                   ptemp, w_mlp_bf, b_mlp, pmlp);
  k4_arc<<<dim3(13, BB), 256, 0, stream>>>(hidden, pmlp, arc_w, labels, outp);
}